// Round 11
// baseline (1768.484 us; speedup 1.0000x reference)
//
#include <hip/hip_runtime.h>
#include <stdint.h>
#include <math.h>

// ---------------- problem constants ----------------
#define T_TOK 2048
#define H_DIM 2880
#define I_DIM 2880
#define E_NUM 16
#define TOPK 4

#define BT 128      // tokens per block tile
#define BK 32       // K chunk
#define NK 90       // K tiles (2880/32)
#define MT_MAX 16   // token tiles per expert
#define NT1 45      // gemm1 output tiles (64 gate + 64 lin rows)
#define NT2 45      // gemm2 output tiles (64 h rows)

typedef __bf16 bf16_t;
typedef __bf16 bf16x8 __attribute__((ext_vector_type(8)));
typedef __bf16 bf16x4 __attribute__((ext_vector_type(4)));
typedef float f32x4 __attribute__((ext_vector_type(4)));

#define WAITV(N) asm volatile("s_waitcnt vmcnt(" #N ")" ::: "memory")
#define WAITL()  asm volatile("s_waitcnt lgkmcnt(0)" ::: "memory")
#define BAR()    asm volatile("s_barrier" ::: "memory")

__device__ __forceinline__ void gload16(const void* g, void* l) {
  __builtin_amdgcn_global_load_lds(
      (__attribute__((address_space(1))) const uint32_t*)g,
      (__attribute__((address_space(3))) uint32_t*)l, 16, 0, 0);
}

__device__ __forceinline__ f32x4 mfma16(bf16x8 a, bf16x8 b, f32x4 c) {
  return __builtin_amdgcn_mfma_f32_16x16x32_bf16(a, b, c, 0, 0, 0);
}

// T LDS layout (R10, measured 0 conflicts): 32x32 bf16 segments, 8-bf16 granules
__device__ __forceinline__ int ldsoff(int row, int g) {
  int r = row & 31;
  return ((row >> 5) << 10) + (((r << 2) + ((g + (r >> 1)) & 3)) << 3);
}
// W LDS layout (fp32): [row][32 f32] linear rows, granule (4 f32) XOR-swizzled.
// elem offset of granule G in row r:
__device__ __forceinline__ int swoff(int row, int G) {
  return row * 32 + (((G) ^ (row & 7)) << 2);
}

// cvt two f32x4 -> bf16x8
__device__ __forceinline__ bf16x8 cvt8(f32x4 a, f32x4 b) {
  bf16x8 o = {(bf16_t)a[0], (bf16_t)a[1], (bf16_t)a[2], (bf16_t)a[3],
              (bf16_t)b[0], (bf16_t)b[1], (bf16_t)b[2], (bf16_t)b[3]};
  return o;
}

// ---------------- prep ----------------
__global__ void k_prep(const float* __restrict__ x, bf16_t* __restrict__ xbf,
                       int* __restrict__ counts) {
  if (blockIdx.x == 0 && threadIdx.x < E_NUM) counts[threadIdx.x] = 0;
  int idx = blockIdx.x * 256 + threadIdx.x;
  const int total = T_TOK * H_DIM / 8;
  if (idx < total) {
    f32x4 a = ((const f32x4*)x)[2 * idx];
    f32x4 b = ((const f32x4*)x)[2 * idx + 1];
    ((bf16x8*)xbf)[idx] = cvt8(a, b);
  }
}

// ---------------- router ----------------
__global__ void k_router(const float* __restrict__ x, const float* __restrict__ gw,
                         const float* __restrict__ gb, float* __restrict__ topw,
                         int* __restrict__ counts, int* __restrict__ rowsl) {
  const int t = blockIdx.x;
  const int lane = threadIdx.x;
  const int c = lane >> 4, e = lane & 15;
  const f32x4* x4 = (const f32x4*)(x + (size_t)t * H_DIM);
  const f32x4* w4 = (const f32x4*)(gw + (size_t)e * H_DIM);
  float p = 0.f;
  const int per = (H_DIM / 4) / 4;
  for (int i = c * per; i < (c + 1) * per; ++i) {
    f32x4 xv = x4[i], wv = w4[i];
    p += xv[0] * wv[0] + xv[1] * wv[1] + xv[2] * wv[2] + xv[3] * wv[3];
  }
  p += __shfl_xor(p, 16);
  p += __shfl_xor(p, 32);
  p += gb[e];
  __shared__ float lg[E_NUM];
  if (lane < E_NUM) lg[lane] = p;
  __syncthreads();
  if (lane == 0) {
    float v[E_NUM];
    #pragma unroll
    for (int i = 0; i < E_NUM; ++i) v[i] = lg[i];
    int idxs[TOPK]; float vals[TOPK];
    for (int k = 0; k < TOPK; ++k) {
      int bi = 0; float bv = -1e30f;
      for (int i = 0; i < E_NUM; ++i) {
        if (v[i] > bv) { bv = v[i]; bi = i; }
      }
      idxs[k] = bi; vals[k] = bv; v[bi] = -1e30f;
    }
    float m = vals[0], s = 0.f, w[TOPK];
    for (int k = 0; k < TOPK; ++k) { w[k] = expf(vals[k] - m); s += w[k]; }
    for (int k = 0; k < TOPK; ++k) {
      int slot = t * TOPK + k;
      topw[slot] = w[k] / s;
      int pos = atomicAdd(&counts[idxs[k]], 1);
      rowsl[idxs[k] * T_TOK + pos] = slot;
    }
  }
}

// ---- T staging (R10 pattern): wave wv stages its 32 rows; 2 gload16/iter ----
#define G_STAGE_T(KT, BUF) do {                                         \
    int c1_ = (KT) > (NK - 1) ? (NK - 1) : (KT);                        \
    _Pragma("unroll")                                                   \
    for (int i_ = 0; i_ < 2; ++i_)                                      \
      gload16(tsrc[i_] + c1_ * BK, &sT[BUF][wv * 1024 + i_ * 512]);     \
  } while (0)

// ============== GEMM1: 128 tok x (64 gate + 64 lin) x K ====================
// Pure global_load_lds for BOTH operands. W fp32 in LDS, cvt at frag read.
// Invariant entering iter k: outstanding = [T_{k+1}(2)]; sW[k&1]=W_k, sT[k%3]=T_k.
// Iter k: issue W_{k+1}(4, FIRST) -> issue T_{k+2}(2) -> MFMA(cur) ->
//         WAITV(2) [retires W_{k+1}, T_{k+1}; keeps T_{k+2}] -> BAR.

#define G1_STAGE_W(KT, BUF) do {                                        \
    int cw_ = (KT) > (NK - 1) ? (NK - 1) : (KT);                        \
    _Pragma("unroll")                                                   \
    for (int i_ = 0; i_ < 4; ++i_)                                      \
      gload16(wsrc[i_] + cw_ * BK, &sWf[BUF][(32 * wv + 8 * i_) * 32]); \
  } while (0)

#define G1_MFMA(SWC, STR) do {                                          \
    const int u_ = lane >> 4, rs_ = lane & 15;                          \
    bf16x8 wg_[2], wl_[2], tf[4];                                       \
    _Pragma("unroll")                                                   \
    for (int wi = 0; wi < 2; ++wi) {                                    \
      int rg = 32 * wm + 16 * wi + rs_;                                 \
      f32x4 a0 = *(const f32x4*)(&sWf[SWC][swoff(rg, 2 * u_)]);         \
      f32x4 a1 = *(const f32x4*)(&sWf[SWC][swoff(rg, 2 * u_ + 1)]);     \
      wg_[wi] = cvt8(a0, a1);                                           \
      f32x4 b0 = *(const f32x4*)(&sWf[SWC][swoff(rg + 64, 2 * u_)]);    \
      f32x4 b1 = *(const f32x4*)(&sWf[SWC][swoff(rg + 64, 2 * u_ + 1)]);\
      wl_[wi] = cvt8(b0, b1);                                           \
    }                                                                   \
    _Pragma("unroll")                                                   \
    for (int tj = 0; tj < 4; ++tj) {                                    \
      int rt = 64 * wt + 16 * tj + rs_;                                 \
      tf[tj] = *(const bf16x8*)(&sT[STR][ldsoff(rt, u_)]);              \
    }                                                                   \
    _Pragma("unroll")                                                   \
    for (int wi = 0; wi < 2; ++wi)                                      \
      _Pragma("unroll")                                                 \
      for (int tj = 0; tj < 4; ++tj) {                                  \
        accg[wi][tj] = mfma16(wg_[wi], tf[tj], accg[wi][tj]);           \
        accl[wi][tj] = mfma16(wl_[wi], tf[tj], accl[wi][tj]);           \
      }                                                                 \
  } while (0)

#define G1_ITER(KK, SWC, STR, STW) do {                                 \
    G1_STAGE_W((KK) + 1, (SWC) ^ 1);                                    \
    G_STAGE_T((KK) + 2, STW);                                           \
    __builtin_amdgcn_s_setprio(1);                                      \
    G1_MFMA(SWC, STR);                                                  \
    __builtin_amdgcn_s_setprio(0);                                      \
    WAITV(2); WAITL(); BAR();                                           \
  } while (0)

__global__ __launch_bounds__(256, 2)
void k_gemm1(const bf16_t* __restrict__ xbf, const float* __restrict__ wgu,
             const float* __restrict__ bgu, const float* __restrict__ al,
             const float* __restrict__ be, const float* __restrict__ lim_,
             const int* __restrict__ counts, const int* __restrict__ rowsl,
             bf16_t* __restrict__ act) {
  const int nwg = E_NUM * NT1 * MT_MAX;   // 11520
  const int L = (blockIdx.x & 7) * (nwg >> 3) + (blockIdx.x >> 3);
  const int mt = L & (MT_MAX - 1);
  const int t2 = L >> 4;
  const int nt = t2 % NT1;
  const int e  = t2 / NT1;
  const int Ne = counts[e];
  const int m0 = mt * BT;
  if (m0 >= Ne) return;
  const int n0 = nt * 64;

  __shared__ alignas(16) float  sWf[2][128 * 32];  // 32 KB, rows 0-63 gate / 64-127 lin
  __shared__ alignas(16) bf16_t sT[3][128 * 32];   // 24 KB

  const int tid = threadIdx.x;
  const int wv = tid >> 6, lane = tid & 63;
  const int wm = wv & 1, wt = wv >> 1;
  const int* rl = rowsl + e * T_TOK;

  // T sources (pre-swizzled for ldsoff layout)
  const bf16_t* tsrc[2];
  {
    #pragma unroll
    for (int i = 0; i < 2; ++i) {
      int q = i * 64 + lane;
      int r = q >> 2;
      int g = ((q & 3) - (r >> 1)) & 3;
      int li = m0 + wv * 32 + r; if (li > Ne - 1) li = Ne - 1;
      int tok = rl[li] >> 2;
      tsrc[i] = xbf + (size_t)tok * H_DIM + g * 8;
    }
  }

  // W sources: wave wv stages rows [32wv, 32wv+32), 4 passes x 8 rows.
  // lane: local row = l>>3, granule g = l&7; source pre-swizzled g^(row&7).
  const float* wsrc[4];
  {
    const int rloc = lane >> 3, g = lane & 7;
    #pragma unroll
    for (int i = 0; i < 4; ++i) {
      int row = 32 * wv + 8 * i + rloc;          // 0..127
      int grow = (row < 64) ? (n0 + row) : (I_DIM + n0 + row - 64);
      wsrc[i] = wgu + (size_t)e * (2 * I_DIM) * H_DIM + (size_t)grow * H_DIM
                + ((g ^ (row & 7)) << 2);
    }
  }

  f32x4 zero = {0.f, 0.f, 0.f, 0.f};
  f32x4 accg[2][4], accl[2][4];
  #pragma unroll
  for (int i = 0; i < 2; ++i)
    #pragma unroll
    for (int j = 0; j < 4; ++j) { accg[i][j] = zero; accl[i][j] = zero; }

  // ---- prologue: W0 -> sWf[0], T0 -> sT[0], T1 -> sT[1]; keep T1 in flight
  G1_STAGE_W(0, 0);     // 4 ops
  G_STAGE_T(0, 0);      // 2 ops
  G_STAGE_T(1, 1);      // 2 ops
  WAITV(2); BAR();      // W0 + T0 landed; [T1(2)] outstanding

  // ---- main loop: 90 iters, 6-unrolled (sW parity 2 x sT cycle 3)
  for (int kb = 0; kb < NK; kb += 6) {
    G1_ITER(kb + 0, 0, 0, 2);
    G1_ITER(kb + 1, 1, 1, 0);
    G1_ITER(kb + 2, 0, 2, 1);
    G1_ITER(kb + 3, 1, 0, 2);
    G1_ITER(kb + 4, 0, 1, 0);
    G1_ITER(kb + 5, 1, 2, 1);
  }

  // ---- epilogue
  const float alpha = al[e], beta = be[e], lim = lim_[e];
  const float* bgp = bgu + (size_t)e * (2 * I_DIM);
  #pragma unroll
  for (int wi = 0; wi < 2; ++wi) {
    const int nb = n0 + 32 * wm + 16 * wi + ((lane >> 4) << 2);
    f32x4 bg4 = *(const f32x4*)(bgp + nb);
    f32x4 bl4 = *(const f32x4*)(bgp + I_DIM + nb);
    #pragma unroll
    for (int tj = 0; tj < 4; ++tj) {
      const int li2 = m0 + 64 * wt + 16 * tj + (lane & 15);
      if (li2 < Ne) {
        const int slot = rl[li2];
        bf16x4 ov;
        #pragma unroll
        for (int r = 0; r < 4; ++r) {
          float g = accg[wi][tj][r] + bg4[r];
          float l = accl[wi][tj][r] + bl4[r];
          g = fminf(g, lim);
          l = fminf(fmaxf(l, -lim), lim);
          float sg = 1.0f / (1.0f + expf(-alpha * g));
          ov[r] = (bf16_t)(g * sg * (l + beta));
        }
        *(bf16x4*)(&act[(size_t)slot * I_DIM + nb]) = ov;
      }
    }
  }
}

// ============== GEMM2: 128 tok x 64 h x K ==================================
// Same structure; W 64 rows -> 2 gloads/wave; 40 KB LDS.

#define G2_STAGE_W(KT, BUF) do {                                        \
    int cw_ = (KT) > (NK - 1) ? (NK - 1) : (KT);                        \
    _Pragma("unroll")                                                   \
    for (int i_ = 0; i_ < 2; ++i_)                                      \
      gload16(wsrc[i_] + cw_ * BK, &sWf[BUF][(16 * wv + 8 * i_) * 32]); \
  } while (0)

#define G2_MFMA(SWC, STR) do {                                          \
    const int u_ = lane >> 4, rs_ = lane & 15;                          \
    bf16x8 wf_[2], tf[4];                                               \
    _Pragma("unroll")                                                   \
    for (int wi = 0; wi < 2; ++wi) {                                    \
      int rg = 32 * wm + 16 * wi + rs_;                                 \
      f32x4 a0 = *(const f32x4*)(&sWf[SWC][swoff(rg, 2 * u_)]);         \
      f32x4 a1 = *(const f32x4*)(&sWf[SWC][swoff(rg, 2 * u_ + 1)]);     \
      wf_[wi] = cvt8(a0, a1);                                           \
    }                                                                   \
    _Pragma("unroll")                                                   \
    for (int tj = 0; tj < 4; ++tj) {                                    \
      int rt = 64 * wt + 16 * tj + rs_;                                 \
      tf[tj] = *(const bf16x8*)(&sT[STR][ldsoff(rt, u_)]);              \
    }                                                                   \
    _Pragma("unroll")                                                   \
    for (int wi = 0; wi < 2; ++wi)                                      \
      _Pragma("unroll")                                                 \
      for (int tj = 0; tj < 4; ++tj)                                    \
        acc[wi][tj] = mfma16(wf_[wi], tf[tj], acc[wi][tj]);             \
  } while (0)

#define G2_ITER(KK, SWC, STR, STW) do {                                 \
    G2_STAGE_W((KK) + 1, (SWC) ^ 1);                                    \
    G_STAGE_T((KK) + 2, STW);                                           \
    __builtin_amdgcn_s_setprio(1);                                      \
    G2_MFMA(SWC, STR);                                                  \
    __builtin_amdgcn_s_setprio(0);                                      \
    WAITV(2); WAITL(); BAR();                                           \
  } while (0)

__global__ __launch_bounds__(256, 3)
void k_gemm2(const bf16_t* __restrict__ act, const float* __restrict__ wd,
             const float* __restrict__ bd, const float* __restrict__ topw,
             const int* __restrict__ counts, const int* __restrict__ rowsl,
             float* __restrict__ ybuf) {
  const int nwg = E_NUM * NT2 * MT_MAX;   // 11520
  const int L = (blockIdx.x & 7) * (nwg >> 3) + (blockIdx.x >> 3);
  const int mt = L & (MT_MAX - 1);
  const int t2 = L >> 4;
  const int ht = t2 % NT2;
  const int e  = t2 / NT2;
  const int Ne = counts[e];
  const int m0 = mt * BT;
  if (m0 >= Ne) return;
  const int h0 = ht * 64;

  __shared__ alignas(16) float  sWf[2][64 * 32];   // 16 KB
  __shared__ alignas(16) bf16_t sT[3][128 * 32];   // 24 KB

  const int tid = threadIdx.x;
  const int wv = tid >> 6, lane = tid & 63;
  const int wm = wv & 1, wt = wv >> 1;
  const int* rl = rowsl + e * T_TOK;

  const bf16_t* tsrc[2];
  {
    #pragma unroll
    for (int i = 0; i < 2; ++i) {
      int q = i * 64 + lane;
      int r = q >> 2;
      int g = ((q & 3) - (r >> 1)) & 3;
      int li = m0 + wv * 32 + r; if (li > Ne - 1) li = Ne - 1;
      int slot = rl[li];
      tsrc[i] = act + (size_t)slot * I_DIM + g * 8;
    }
  }

  // W sources: wave wv stages rows [16wv, 16wv+16), 2 passes x 8 rows
  const float* wsrc[2];
  {
    const int rloc = lane >> 3, g = lane & 7;
    #pragma unroll
    for (int i = 0; i < 2; ++i) {
      int row = 16 * wv + 8 * i + rloc;          // 0..63
      wsrc[i] = wd + (size_t)e * H_DIM * I_DIM + (size_t)(h0 + row) * I_DIM
                + ((g ^ (row & 7)) << 2);
    }
  }

  f32x4 zero = {0.f, 0.f, 0.f, 0.f};
  f32x4 acc[2][4];
  #pragma unroll
  for (int i = 0; i < 2; ++i)
    #pragma unroll
    for (int j = 0; j < 4; ++j) acc[i][j] = zero;

  G2_STAGE_W(0, 0);
  G_STAGE_T(0, 0);
  G_STAGE_T(1, 1);
  WAITV(2); BAR();

  for (int kb = 0; kb < NK; kb += 6) {
    G2_ITER(kb + 0, 0, 0, 2);
    G2_ITER(kb + 1, 1, 1, 0);
    G2_ITER(kb + 2, 0, 2, 1);
    G2_ITER(kb + 3, 1, 0, 2);
    G2_ITER(kb + 4, 0, 1, 0);
    G2_ITER(kb + 5, 1, 2, 1);
  }

  const float* bdp = bd + (size_t)e * H_DIM;
  #pragma unroll
  for (int wi = 0; wi < 2; ++wi) {
    const int hb = h0 + 32 * wm + 16 * wi + ((lane >> 4) << 2);
    f32x4 b4 = *(const f32x4*)(bdp + hb);
    #pragma unroll
    for (int tj = 0; tj < 4; ++tj) {
      const int li2 = m0 + 64 * wt + 16 * tj + (lane & 15);
      if (li2 < Ne) {
        const int slot = rl[li2];
        const float tw = topw[slot];
        f32x4 o = (acc[wi][tj] + b4) * tw;
        *(f32x4*)(&ybuf[(size_t)slot * H_DIM + hb]) = o;
      }
    }
  }
}

// ---------------- combine ----------------------
__global__ void k_combine(const float* __restrict__ ybuf, float* __restrict__ out) {
  const int j4 = H_DIM / 4;
  int idx = blockIdx.x * 256 + threadIdx.x;
  if (idx >= T_TOK * j4) return;
  int t = idx / j4, j = idx - t * j4;
  const f32x4* yb = (const f32x4*)ybuf;
  f32x4 s = yb[(size_t)(t * 4 + 0) * j4 + j];
  s = s + yb[(size_t)(t * 4 + 1) * j4 + j];
  s = s + yb[(size_t)(t * 4 + 2) * j4 + j];
  s = s + yb[(size_t)(t * 4 + 3) * j4 + j];
  ((f32x4*)out)[idx] = s;
}

// ---------------- host launcher ----------------
extern "C" void kernel_launch(void* const* d_in, const int* in_sizes, int n_in,
                              void* d_out, int out_size, void* d_ws, size_t ws_size,
                              hipStream_t stream) {
  const float* x   = (const float*)d_in[0];
  const float* gw  = (const float*)d_in[1];
  const float* gb  = (const float*)d_in[2];
  const float* wgu = (const float*)d_in[3];
  const float* bgu = (const float*)d_in[4];
  const float* wd  = (const float*)d_in[5];
  const float* bd  = (const float*)d_in[6];
  const float* sal = (const float*)d_in[7];
  const float* sbe = (const float*)d_in[8];
  const float* sli = (const float*)d_in[9];
  float* out = (float*)d_out;

  char* ws = (char*)d_ws;
  int*    counts = (int*)(ws + 0);
  int*    rowsl  = (int*)(ws + 4096);
  float*  topw   = (float*)(ws + 4096 + 131072);
  bf16_t* xbf    = (bf16_t*)(ws + (1 << 20));
  bf16_t* act    = (bf16_t*)(ws + (size_t)(16 << 20));
  float*  ybuf   = (float*)(ws + (size_t)(64 << 20));

  k_prep<<<dim3(2880), dim3(256), 0, stream>>>(x, xbf, counts);
  k_router<<<dim3(T_TOK), dim3(64), 0, stream>>>(x, gw, gb, topw, counts, rowsl);
  k_gemm1<<<dim3(E_NUM * NT1 * MT_MAX), dim3(256), 0, stream>>>(
      xbf, wgu, bgu, sal, sbe, sli, counts, rowsl, act);
  k_gemm2<<<dim3(E_NUM * NT2 * MT_MAX), dim3(256), 0, stream>>>(
      act, wd, bd, topw, counts, rowsl, ybuf);
  k_combine<<<dim3(5760), dim3(256), 0, stream>>>(ybuf, out);
}

// Round 12
// 1465.211 us; speedup vs baseline: 1.2070x; 1.2070x over previous
//
#include <hip/hip_runtime.h>
#include <stdint.h>
#include <math.h>

// ---------------- problem constants ----------------
#define T_TOK 2048
#define H_DIM 2880
#define I_DIM 2880
#define E_NUM 16
#define TOPK 4

#define BT 256      // tokens per block tile
#define BK 64       // K chunk (elements)
#define NK 45       // K tiles (2880/64)
#define MT_MAX 8    // token tiles per expert (2048/256)
#define NT1 30      // gemm1 output tiles (96 gate + 96 lin rows each)
#define NT2 15      // gemm2 output tiles (192 h rows each)

typedef __bf16 bf16_t;
typedef __bf16 bf16x8 __attribute__((ext_vector_type(8)));
typedef __bf16 bf16x4 __attribute__((ext_vector_type(4)));
typedef float f32x4 __attribute__((ext_vector_type(4)));

#define WAITV(N) asm volatile("s_waitcnt vmcnt(" #N ")" ::: "memory")
#define WAITL()  asm volatile("s_waitcnt lgkmcnt(0)" ::: "memory")
#define BAR()    asm volatile("s_barrier" ::: "memory")

__device__ __forceinline__ void gload16(const void* g, void* l) {
  __builtin_amdgcn_global_load_lds(
      (__attribute__((address_space(1))) const uint32_t*)g,
      (__attribute__((address_space(3))) uint32_t*)l, 16, 0, 0);
}

__device__ __forceinline__ f32x4 mfma16(bf16x8 a, bf16x8 b, f32x4 c) {
  return __builtin_amdgcn_mfma_f32_16x16x32_bf16(a, b, c, 0, 0, 0);
}

// LDS layout for [rows][64] bf16 tiles: 32-row segments, 8-elem granules,
// granule position gd = (g + (row&7)) & 7  -> frag reads are 2-way (free).
__device__ __forceinline__ int loff(int row, int g) {
  return ((row >> 5) << 11) + ((row & 31) << 6) + (((g + (row & 7)) & 7) << 3);
}

__device__ __forceinline__ bf16x4 cvt4(f32x4 a) {
  bf16x4 o = {(bf16_t)a[0], (bf16_t)a[1], (bf16_t)a[2], (bf16_t)a[3]};
  return o;
}

// ---------------- prep: x -> bf16, zero counts ----------------
__global__ void k_prep(const float* __restrict__ x, bf16_t* __restrict__ xbf,
                       int* __restrict__ counts) {
  if (blockIdx.x == 0 && threadIdx.x < E_NUM) counts[threadIdx.x] = 0;
  int idx = blockIdx.x * 256 + threadIdx.x;
  const int total = T_TOK * H_DIM / 8;
  if (idx < total) {
    f32x4 a = ((const f32x4*)x)[2 * idx];
    f32x4 b = ((const f32x4*)x)[2 * idx + 1];
    bf16x8 o = {(bf16_t)a[0], (bf16_t)a[1], (bf16_t)a[2], (bf16_t)a[3],
                (bf16_t)b[0], (bf16_t)b[1], (bf16_t)b[2], (bf16_t)b[3]};
    ((bf16x8*)xbf)[idx] = o;
  }
}

// ---------------- router ----------------
__global__ void k_router(const float* __restrict__ x, const float* __restrict__ gw,
                         const float* __restrict__ gb, float* __restrict__ topw,
                         int* __restrict__ counts, int* __restrict__ rowsl) {
  const int t = blockIdx.x;
  const int lane = threadIdx.x;
  const int c = lane >> 4, e = lane & 15;
  const f32x4* x4 = (const f32x4*)(x + (size_t)t * H_DIM);
  const f32x4* w4 = (const f32x4*)(gw + (size_t)e * H_DIM);
  float p = 0.f;
  const int per = (H_DIM / 4) / 4;
  for (int i = c * per; i < (c + 1) * per; ++i) {
    f32x4 xv = x4[i], wv = w4[i];
    p += xv[0] * wv[0] + xv[1] * wv[1] + xv[2] * wv[2] + xv[3] * wv[3];
  }
  p += __shfl_xor(p, 16);
  p += __shfl_xor(p, 32);
  p += gb[e];
  __shared__ float lg[E_NUM];
  if (lane < E_NUM) lg[lane] = p;
  __syncthreads();
  if (lane == 0) {
    float v[E_NUM];
    #pragma unroll
    for (int i = 0; i < E_NUM; ++i) v[i] = lg[i];
    int idxs[TOPK]; float vals[TOPK];
    for (int k = 0; k < TOPK; ++k) {
      int bi = 0; float bv = -1e30f;
      for (int i = 0; i < E_NUM; ++i) {
        if (v[i] > bv) { bv = v[i]; bi = i; }
      }
      idxs[k] = bi; vals[k] = bv; v[bi] = -1e30f;
    }
    float m = vals[0], s = 0.f, w[TOPK];
    for (int k = 0; k < TOPK; ++k) { w[k] = expf(vals[k] - m); s += w[k]; }
    for (int k = 0; k < TOPK; ++k) {
      int slot = t * TOPK + k;
      topw[slot] = w[k] / s;
      int pos = atomicAdd(&counts[idxs[k]], 1);
      rowsl[idxs[k] * T_TOK + pos] = slot;
    }
  }
}

// ---- T staging: wave wv stages rows [16wv,16wv+16) of 256-row tile ----
// dest linear: sT[buf] + wv*1024 + q*8  (q = i*64 + lane), source pre-swizzled.
#define G_STAGE_T(KT, BUF) do {                                         \
    int c1_ = (KT) > (NK - 1) ? (NK - 1) : (KT);                        \
    _Pragma("unroll")                                                   \
    for (int i_ = 0; i_ < 2; ++i_)                                      \
      gload16(tsrc[i_] + c1_ * BK,                                      \
              &sT[BUF][wv * 1024 + i_ * 512 + lane * 8]);               \
  } while (0)

// ============== GEMM1: 256 tok x (96 gate + 96 lin) x K ====================
// 1024 threads / 16 waves: wt = wv&7 (32-token group), wo = wv>>3 (48-row half).
// Single-barrier counted-vmcnt (R4): invariant entering iter j:
// outstanding = [W_{j+2}(3)]; sW[j&1]=W_j, sT[j&1]=T_j, wset=W_{j+1} (regs).
// Iter j: stage T_{j+1}(2) -> ds_write W_{j+1} -> load W_{j+3}(3) -> MFMA ->
//         WAITV(3) [retires W_{j+2}, T_{j+1}] -> lgkm(0) -> barrier.

#define G1_MFMA(CUR) do {                                               \
    _Pragma("unroll")                                                   \
    for (int ks = 0; ks < 2; ++ks) {                                    \
      const int gk = 4 * ks + u;                                        \
      bf16x8 wg_[3], wl_[3], tf[2];                                     \
      _Pragma("unroll")                                                 \
      for (int f = 0; f < 3; ++f) {                                     \
        int rg = 48 * wo + 16 * f + rs;                                 \
        wg_[f] = *(const bf16x8*)(&sW[CUR][loff(rg, gk)]);              \
        wl_[f] = *(const bf16x8*)(&sW[CUR][loff(rg + 96, gk)]);         \
      }                                                                 \
      _Pragma("unroll")                                                 \
      for (int tj = 0; tj < 2; ++tj) {                                  \
        int rt = 32 * wt + 16 * tj + rs;                                \
        tf[tj] = *(const bf16x8*)(&sT[CUR][loff(rt, gk)]);              \
      }                                                                 \
      _Pragma("unroll")                                                 \
      for (int f = 0; f < 3; ++f)                                       \
        _Pragma("unroll")                                               \
        for (int tj = 0; tj < 2; ++tj) {                                \
          accg[f][tj] = mfma16(wg_[f], tf[tj], accg[f][tj]);            \
          accl[f][tj] = mfma16(wl_[f], tf[tj], accl[f][tj]);            \
        }                                                               \
    }                                                                   \
  } while (0)

#define G1_ITER(KK, WSET) do {                                          \
    const int cur_ = (KK) & 1;                                          \
    G_STAGE_T((KK) + 1, cur_ ^ 1);                                      \
    _Pragma("unroll")                                                   \
    for (int p_ = 0; p_ < 3; ++p_)                                      \
      *(bf16x4*)(&sW[cur_ ^ 1][woff[p_]]) = cvt4(WSET[p_]);             \
    { int c3_ = (KK) + 3 > (NK - 1) ? (NK - 1) : (KK) + 3;              \
      _Pragma("unroll")                                                 \
      for (int p_ = 0; p_ < 3; ++p_)                                    \
        WSET[p_] = *(const f32x4*)(wsrc[p_] + c3_ * BK); }              \
    __builtin_amdgcn_s_setprio(1);                                      \
    G1_MFMA(cur_);                                                      \
    __builtin_amdgcn_s_setprio(0);                                      \
    WAITV(3); WAITL(); BAR();                                           \
  } while (0)

__global__ __launch_bounds__(1024, 4)
void k_gemm1(const bf16_t* __restrict__ xbf, const float* __restrict__ wgu,
             const float* __restrict__ bgu, const float* __restrict__ al,
             const float* __restrict__ be, const float* __restrict__ lim_,
             const int* __restrict__ counts, const int* __restrict__ rowsl,
             bf16_t* __restrict__ act) {
  const int nwg = E_NUM * NT1 * MT_MAX;   // 3840
  const int L = (blockIdx.x & 7) * (nwg >> 3) + (blockIdx.x >> 3);
  const int mt = L & (MT_MAX - 1);
  const int t2 = L >> 3;
  const int nt = t2 % NT1;
  const int e  = t2 / NT1;
  const int Ne = counts[e];
  const int m0 = mt * BT;
  if (m0 >= Ne) return;
  const int n0 = nt * 96;

  __shared__ alignas(16) bf16_t sW[2][192 * 64];  // 48 KB (0-95 gate, 96-191 lin)
  __shared__ alignas(16) bf16_t sT[2][256 * 64];  // 64 KB

  const int tid = threadIdx.x;
  const int wv = tid >> 6, lane = tid & 63;
  const int wt = wv & 7, wo = wv >> 3;
  const int u = lane >> 4, rs = lane & 15;
  const int* rl = rowsl + e * T_TOK;

  // T sources: lane covers dest granule q = i*64+lane; row = 16wv + (q>>3)
  const bf16_t* tsrc[2];
  {
    #pragma unroll
    for (int i = 0; i < 2; ++i) {
      int q = i * 64 + lane;
      int row = 16 * wv + (q >> 3);
      int gd = q & 7;
      int g = (gd - (row & 7)) & 7;
      int li = m0 + row; if (li > Ne - 1) li = Ne - 1;
      int tok = rl[li] >> 2;
      tsrc[i] = xbf + (size_t)tok * H_DIM + g * 8;
    }
  }

  // W staging: 3 passes of 64 rows; 16 thr/row (wf), f32x4 at col wf*4
  const int wrow = tid >> 4, wf = tid & 15;
  const float* wsrc[3];
  int woff[3];
  #pragma unroll
  for (int p = 0; p < 3; ++p) {
    int row = 64 * p + wrow;   // 0..191
    int grow = (row < 96) ? (n0 + row) : (I_DIM + n0 + row - 96);
    wsrc[p] = wgu + ((size_t)e * 2 * I_DIM + grow) * H_DIM + wf * 4;
    woff[p] = loff(row, wf >> 1) + (wf & 1) * 4;
  }

  f32x4 zero = {0.f, 0.f, 0.f, 0.f};
  f32x4 accg[3][2], accl[3][2];
  #pragma unroll
  for (int i = 0; i < 3; ++i)
    #pragma unroll
    for (int j = 0; j < 2; ++j) { accg[i][j] = zero; accl[i][j] = zero; }

  f32x4 wA[3], wB[3];
  // ---- prologue: sW[0]=W0, sT[0]=T0; wA=W1 retired; wB=W2 in flight ----
  #pragma unroll
  for (int p = 0; p < 3; ++p) wA[p] = *(const f32x4*)(wsrc[p]);         // W0
  WAITV(0);
  #pragma unroll
  for (int p = 0; p < 3; ++p) *(bf16x4*)(&sW[0][woff[p]]) = cvt4(wA[p]);
  G_STAGE_T(0, 0);                                                      // T0 (2)
  #pragma unroll
  for (int p = 0; p < 3; ++p) wA[p] = *(const f32x4*)(wsrc[p] + BK);    // W1 (3)
  #pragma unroll
  for (int p = 0; p < 3; ++p) wB[p] = *(const f32x4*)(wsrc[p] + 2 * BK);// W2 (3)
  WAITV(3);   // retires T0 + W1; leaves [W2(3)]
  WAITL(); BAR();

  // ---- main loop: 45 iters = 22 pairs + 1
  for (int kb = 0; kb < NK - 1; kb += 2) {
    G1_ITER(kb, wA);
    G1_ITER(kb + 1, wB);
  }
  G1_ITER(NK - 1, wA);

  // ---- epilogue
  const float alpha = al[e], beta = be[e], lim = lim_[e];
  const float* bgp = bgu + (size_t)e * (2 * I_DIM);
  #pragma unroll
  for (int f = 0; f < 3; ++f) {
    const int nb = n0 + 48 * wo + 16 * f + 4 * u;
    f32x4 bg4 = *(const f32x4*)(bgp + nb);
    f32x4 bl4 = *(const f32x4*)(bgp + I_DIM + nb);
    #pragma unroll
    for (int tj = 0; tj < 2; ++tj) {
      const int li2 = m0 + 32 * wt + 16 * tj + rs;
      if (li2 < Ne) {
        const int slot = rl[li2];
        bf16x4 ov;
        #pragma unroll
        for (int r = 0; r < 4; ++r) {
          float g = accg[f][tj][r] + bg4[r];
          float l = accl[f][tj][r] + bl4[r];
          g = fminf(g, lim);
          l = fminf(fmaxf(l, -lim), lim);
          float sg = 1.0f / (1.0f + expf(-alpha * g));
          ov[r] = (bf16_t)(g * sg * (l + beta));
        }
        *(bf16x4*)(&act[(size_t)slot * I_DIM + nb]) = ov;
      }
    }
  }
}

// ============== GEMM2: 256 tok x 192 h x K ================================
// Same structure; wave covers 32 tok x 96 h (6 h-frags x 2 tok-frags).

#define G2_MFMA(CUR) do {                                               \
    _Pragma("unroll")                                                   \
    for (int ks = 0; ks < 2; ++ks) {                                    \
      const int gk = 4 * ks + u;                                        \
      bf16x8 wf_[6], tf[2];                                             \
      _Pragma("unroll")                                                 \
      for (int f = 0; f < 6; ++f) {                                     \
        int rg = 96 * wo + 16 * f + rs;                                 \
        wf_[f] = *(const bf16x8*)(&sW[CUR][loff(rg, gk)]);              \
      }                                                                 \
      _Pragma("unroll")                                                 \
      for (int tj = 0; tj < 2; ++tj) {                                  \
        int rt = 32 * wt + 16 * tj + rs;                                \
        tf[tj] = *(const bf16x8*)(&sT[CUR][loff(rt, gk)]);              \
      }                                                                 \
      _Pragma("unroll")                                                 \
      for (int f = 0; f < 6; ++f)                                       \
        _Pragma("unroll")                                               \
        for (int tj = 0; tj < 2; ++tj)                                  \
          acc[f][tj] = mfma16(wf_[f], tf[tj], acc[f][tj]);              \
    }                                                                   \
  } while (0)

#define G2_ITER(KK, WSET) do {                                          \
    const int cur_ = (KK) & 1;                                          \
    G_STAGE_T((KK) + 1, cur_ ^ 1);                                      \
    _Pragma("unroll")                                                   \
    for (int p_ = 0; p_ < 3; ++p_)                                      \
      *(bf16x4*)(&sW[cur_ ^ 1][woff[p_]]) = cvt4(WSET[p_]);             \
    { int c3_ = (KK) + 3 > (NK - 1) ? (NK - 1) : (KK) + 3;              \
      _Pragma("unroll")                                                 \
      for (int p_ = 0; p_ < 3; ++p_)                                    \
        WSET[p_] = *(const f32x4*)(wsrc[p_] + c3_ * BK); }              \
    __builtin_amdgcn_s_setprio(1);                                      \
    G2_MFMA(cur_);                                                      \
    __builtin_amdgcn_s_setprio(0);                                      \
    WAITV(3); WAITL(); BAR();                                           \
  } while (0)

__global__ __launch_bounds__(1024, 4)
void k_gemm2(const bf16_t* __restrict__ act, const float* __restrict__ wd,
             const float* __restrict__ bd, const float* __restrict__ topw,
             const int* __restrict__ counts, const int* __restrict__ rowsl,
             float* __restrict__ ybuf) {
  const int nwg = E_NUM * NT2 * MT_MAX;   // 1920
  const int L = (blockIdx.x & 7) * (nwg >> 3) + (blockIdx.x >> 3);
  const int mt = L & (MT_MAX - 1);
  const int t2 = L >> 3;
  const int ht = t2 % NT2;
  const int e  = t2 / NT2;
  const int Ne = counts[e];
  const int m0 = mt * BT;
  if (m0 >= Ne) return;
  const int h0 = ht * 192;

  __shared__ alignas(16) bf16_t sW[2][192 * 64];  // 48 KB
  __shared__ alignas(16) bf16_t sT[2][256 * 64];  // 64 KB

  const int tid = threadIdx.x;
  const int wv = tid >> 6, lane = tid & 63;
  const int wt = wv & 7, wo = wv >> 3;
  const int u = lane >> 4, rs = lane & 15;
  const int* rl = rowsl + e * T_TOK;

  const bf16_t* tsrc[2];
  {
    #pragma unroll
    for (int i = 0; i < 2; ++i) {
      int q = i * 64 + lane;
      int row = 16 * wv + (q >> 3);
      int gd = q & 7;
      int g = (gd - (row & 7)) & 7;
      int li = m0 + row; if (li > Ne - 1) li = Ne - 1;
      int slot = rl[li];
      tsrc[i] = act + (size_t)slot * I_DIM + g * 8;
    }
  }

  const int wrow = tid >> 4, wf = tid & 15;
  const float* wsrc[3];
  int woff[3];
  #pragma unroll
  for (int p = 0; p < 3; ++p) {
    int row = 64 * p + wrow;   // 0..191
    wsrc[p] = wd + ((size_t)e * H_DIM + (h0 + row)) * I_DIM + wf * 4;
    woff[p] = loff(row, wf >> 1) + (wf & 1) * 4;
  }

  f32x4 zero = {0.f, 0.f, 0.f, 0.f};
  f32x4 acc[6][2];
  #pragma unroll
  for (int i = 0; i < 6; ++i)
    #pragma unroll
    for (int j = 0; j < 2; ++j) acc[i][j] = zero;

  f32x4 wA[3], wB[3];
  #pragma unroll
  for (int p = 0; p < 3; ++p) wA[p] = *(const f32x4*)(wsrc[p]);         // W0
  WAITV(0);
  #pragma unroll
  for (int p = 0; p < 3; ++p) *(bf16x4*)(&sW[0][woff[p]]) = cvt4(wA[p]);
  G_STAGE_T(0, 0);                                                      // T0 (2)
  #pragma unroll
  for (int p = 0; p < 3; ++p) wA[p] = *(const f32x4*)(wsrc[p] + BK);    // W1
  #pragma unroll
  for (int p = 0; p < 3; ++p) wB[p] = *(const f32x4*)(wsrc[p] + 2 * BK);// W2
  WAITV(3); WAITL(); BAR();

  for (int kb = 0; kb < NK - 1; kb += 2) {
    G2_ITER(kb, wA);
    G2_ITER(kb + 1, wB);
  }
  G2_ITER(NK - 1, wA);

  const float* bdp = bd + (size_t)e * H_DIM;
  #pragma unroll
  for (int f = 0; f < 6; ++f) {
    const int hb = h0 + 96 * wo + 16 * f + 4 * u;
    f32x4 b4 = *(const f32x4*)(bdp + hb);
    #pragma unroll
    for (int tj = 0; tj < 2; ++tj) {
      const int li2 = m0 + 32 * wt + 16 * tj + rs;
      if (li2 < Ne) {
        const int slot = rl[li2];
        const float tw = topw[slot];
        f32x4 o = (acc[f][tj] + b4) * tw;
        *(f32x4*)(&ybuf[(size_t)slot * H_DIM + hb]) = o;
      }
    }
  }
}

// ---------------- combine ----------------------
__global__ void k_combine(const float* __restrict__ ybuf, float* __restrict__ out) {
  const int j4 = H_DIM / 4;
  int idx = blockIdx.x * 256 + threadIdx.x;
  if (idx >= T_TOK * j4) return;
  int t = idx / j4, j = idx - t * j4;
  const f32x4* yb = (const f32x4*)ybuf;
  f32x4 s = yb[(size_t)(t * 4 + 0) * j4 + j];
  s = s + yb[(size_t)(t * 4 + 1) * j4 + j];
  s = s + yb[(size_t)(t * 4 + 2) * j4 + j];
  s = s + yb[(size_t)(t * 4 + 3) * j4 + j];
  ((f32x4*)out)[idx] = s;
}

// ---------------- host launcher ----------------
extern "C" void kernel_launch(void* const* d_in, const int* in_sizes, int n_in,
                              void* d_out, int out_size, void* d_ws, size_t ws_size,
                              hipStream_t stream) {
  const float* x   = (const float*)d_in[0];
  const float* gw  = (const float*)d_in[1];
  const float* gb  = (const float*)d_in[2];
  const float* wgu = (const float*)d_in[3];
  const float* bgu = (const float*)d_in[4];
  const float* wd  = (const float*)d_in[5];
  const float* bd  = (const float*)d_in[6];
  const float* sal = (const float*)d_in[7];
  const float* sbe = (const float*)d_in[8];
  const float* sli = (const float*)d_in[9];
  float* out = (float*)d_out;

  char* ws = (char*)d_ws;
  int*    counts = (int*)(ws + 0);
  int*    rowsl  = (int*)(ws + 4096);
  float*  topw   = (float*)(ws + 4096 + 131072);
  bf16_t* xbf    = (bf16_t*)(ws + (1 << 20));
  bf16_t* act    = (bf16_t*)(ws + (size_t)(16 << 20));
  float*  ybuf   = (float*)(ws + (size_t)(64 << 20));

  k_prep<<<dim3(2880), dim3(256), 0, stream>>>(x, xbf, counts);
  k_router<<<dim3(T_TOK), dim3(64), 0, stream>>>(x, gw, gb, topw, counts, rowsl);
  k_gemm1<<<dim3(E_NUM * NT1 * MT_MAX), dim3(1024), 0, stream>>>(
      xbf, wgu, bgu, sal, sbe, sli, counts, rowsl, act);
  k_gemm2<<<dim3(E_NUM * NT2 * MT_MAX), dim3(1024), 0, stream>>>(
      act, wd, bd, topw, counts, rowsl, ybuf);
  k_combine<<<dim3(5760), dim3(256), 0, stream>>>(ybuf, out);
}